// Round 1
// baseline (318.367 us; speedup 1.0000x reference)
//
#include <hip/hip_runtime.h>
#include <hip/hip_fp16.h>
#include <math.h>

#define BH_N 96
#define S_N 4096
#define D_N 64
#define TOPK 128

__device__ __forceinline__ unsigned long long orderKey(double d) {
  unsigned long long u = (unsigned long long)__double_as_longlong(d);
  if (u & 0x8000000000000000ULL) u = ~u;
  else u |= 0x8000000000000000ULL;
  return u;  // monotonic: a<b (double) <=> orderKey(a)<orderKey(b)
}

// Kernel A: importance (double-precision mean + std, ddof=1) + zero-fill out.
// One block = 16 rows of 64 floats; 16 lanes per row; float4 per lane.
__global__ __launch_bounds__(256)
void imp_zero_kernel(const float* __restrict__ q, float* __restrict__ out,
                     double* __restrict__ imp) {
  const int tid = threadIdx.x;
  const size_t off = (size_t)blockIdx.x * 1024 + (size_t)tid * 4;
  const float4 v = *reinterpret_cast<const float4*>(q + off);
  float4 z; z.x = z.y = z.z = z.w = 0.f;
  *reinterpret_cast<float4*>(out + off) = z;

  double s  = (double)v.x + (double)v.y + (double)v.z + (double)v.w;
  double ss = (double)v.x * v.x + (double)v.y * v.y +
              (double)v.z * v.z + (double)v.w * v.w;
#pragma unroll
  for (int m = 1; m < 16; m <<= 1) {
    s  += __shfl_xor(s, m, 64);
    ss += __shfl_xor(ss, m, 64);
  }
  if ((tid & 15) == 0) {
    double mean = s * (1.0 / 64.0);
    double var = (ss - s * s * (1.0 / 64.0)) * (1.0 / 63.0);
    if (var < 0.0) var = 0.0;
    imp[(size_t)blockIdx.x * 16 + (tid >> 4)] = mean + sqrt(var);
  }
}

// Kernel B: per-(b,h) top-128 select + 128x128x64 attention + scatter.
__global__ __launch_bounds__(256)
void topk_attn_kernel(const float* __restrict__ q, const float* __restrict__ k,
                      const float* __restrict__ v, const double* __restrict__ imp,
                      float* __restrict__ out) {
  __shared__ __align__(16) float sA[8448];  // q_s [128][65] fp32, later P [128][132] fp16
  __shared__ __align__(16) float sB[4160];  // k/v half [64][65] fp32
  __shared__ int s_idx[TOPK];
  __shared__ int s_red[4];
  __shared__ int s_cnt;

  const int tid = threadIdx.x;
  const int lane = tid & 63;
  const int wv = tid >> 6;
  const int bh = blockIdx.x;
  const double* impb = imp + (size_t)bh * S_N;

  // ---- phase 0: keys into registers (coalesced: index = i*256 + tid)
  unsigned long long key[16];
#pragma unroll
  for (int i = 0; i < 16; ++i) key[i] = orderKey(impb[i * 256 + tid]);

  // ---- binary search for T = 128th largest key
  unsigned long long lo = 0ULL, hi = ~0ULL;
  while (lo < hi) {
    unsigned long long d = hi - lo;
    unsigned long long mid = lo + (d >> 1) + (d & 1ULL);  // ceil, overflow-safe
    int c = 0;
#pragma unroll
    for (int i = 0; i < 16; ++i) c += (key[i] >= mid) ? 1 : 0;
#pragma unroll
    for (int m = 1; m < 64; m <<= 1) c += __shfl_xor(c, m, 64);
    if (lane == 0) s_red[wv] = c;
    __syncthreads();
    int total = s_red[0] + s_red[1] + s_red[2] + s_red[3];
    __syncthreads();
    if (total >= TOPK) lo = mid; else hi = mid - 1;
  }
  const unsigned long long T = lo;

  // ---- emit strictly-greater (set semantics, order-free)
  if (tid == 0) s_cnt = 0;
  __syncthreads();
#pragma unroll
  for (int i = 0; i < 16; ++i) {
    if (key[i] > T) {
      int slot = atomicAdd(&s_cnt, 1);
      s_idx[slot] = i * 256 + tid;
    }
  }
  __syncthreads();
  const int nsel = s_cnt;
  const int need = TOPK - nsel;
  // ---- ties at T: fill with lowest indices first (top_k tie-break)
  if (wv == 0 && need > 0) {
    int running = 0;
    for (int base = 0; base < S_N && running < need; base += 64) {
      unsigned long long kk2 = orderKey(impb[base + lane]);
      unsigned long long mask = __ballot(kk2 == T);
      if (kk2 == T) {
        int below = __popcll(mask & ((1ULL << lane) - 1ULL));
        int pos = running + below;
        if (pos < need) s_idx[nsel + pos] = base + lane;
      }
      running += __popcll(mask);
    }
  }
  __syncthreads();

  const size_t baseQ = (size_t)bh * S_N * D_N;
  const int rgrp = tid >> 4;        // 0..15
  const int c4 = (tid & 15) * 4;    // 0..60

  // ---- gather q_s -> sA [128][65]
#pragma unroll
  for (int it = 0; it < 8; ++it) {
    int r = it * 16 + rgrp;
    int srow = s_idx[r];
    float4 val = *reinterpret_cast<const float4*>(q + baseQ + (size_t)srow * D_N + c4);
    sA[r * 65 + c4 + 0] = val.x;
    sA[r * 65 + c4 + 1] = val.y;
    sA[r * 65 + c4 + 2] = val.z;
    sA[r * 65 + c4 + 3] = val.w;
  }

  // ---- QK^T: thread (tq,sq) -> rows 8tq..8tq+7, cols (64h + 4sq..4sq+3)
  float acc[8][8];
#pragma unroll
  for (int j = 0; j < 8; ++j)
#pragma unroll
    for (int m = 0; m < 8; ++m) acc[j][m] = 0.f;

  const int tq = tid >> 4;
  const int sq = tid & 15;

  for (int h = 0; h < 2; ++h) {
    __syncthreads();  // gather/previous-half reads complete before sB overwrite
#pragma unroll
    for (int it = 0; it < 4; ++it) {
      int r = it * 16 + rgrp;  // 0..63
      int srow = s_idx[h * 64 + r];
      float4 val = *reinterpret_cast<const float4*>(k + baseQ + (size_t)srow * D_N + c4);
      sB[r * 65 + c4 + 0] = val.x;
      sB[r * 65 + c4 + 1] = val.y;
      sB[r * 65 + c4 + 2] = val.z;
      sB[r * 65 + c4 + 3] = val.w;
    }
    __syncthreads();
    for (int kk = 0; kk < 64; ++kk) {
      float qv[8], kv[4];
#pragma unroll
      for (int j = 0; j < 8; ++j) qv[j] = sA[(8 * tq + j) * 65 + kk];
#pragma unroll
      for (int m = 0; m < 4; ++m) kv[m] = sB[(4 * sq + m) * 65 + kk];
#pragma unroll
      for (int j = 0; j < 8; ++j)
#pragma unroll
        for (int m = 0; m < 4; ++m) acc[j][h * 4 + m] += qv[j] * kv[m];
    }
  }
  __syncthreads();  // all QK LDS reads done; sA may be reused for P

  // ---- softmax in registers (reduce across sq = 16 consecutive lanes)
  __half* sP = reinterpret_cast<__half*>(sA);  // [128][132] halves
  float rmax[8], rsum[8];
#pragma unroll
  for (int j = 0; j < 8; ++j) {
    float mx = acc[j][0];
#pragma unroll
    for (int m = 1; m < 8; ++m) mx = fmaxf(mx, acc[j][m]);
    rmax[j] = mx;
  }
#pragma unroll
  for (int mm = 1; mm < 16; mm <<= 1)
#pragma unroll
    for (int j = 0; j < 8; ++j) rmax[j] = fmaxf(rmax[j], __shfl_xor(rmax[j], mm, 64));
#pragma unroll
  for (int j = 0; j < 8; ++j) {
    float sum = 0.f;
#pragma unroll
    for (int m = 0; m < 8; ++m) {
      float p = __expf(0.125f * (acc[j][m] - rmax[j]));  // scale 1/sqrt(64)
      acc[j][m] = p;
      sum += p;
    }
    rsum[j] = sum;
  }
#pragma unroll
  for (int mm = 1; mm < 16; mm <<= 1)
#pragma unroll
    for (int j = 0; j < 8; ++j) rsum[j] += __shfl_xor(rsum[j], mm, 64);
#pragma unroll
  for (int j = 0; j < 8; ++j) {
    float rinv = 1.f / rsum[j];
#pragma unroll
    for (int h2 = 0; h2 < 2; ++h2)
#pragma unroll
      for (int m = 0; m < 4; ++m) {
        int col = h2 * 64 + 4 * sq + m;
        sP[(8 * tq + j) * 132 + col] = __float2half_rn(acc[j][h2 * 4 + m] * rinv);
      }
  }

  // ---- PV: thread (ti,di) -> out rows 8ti..8ti+7, cols 4di..4di+3
  float acc2[8][4];
#pragma unroll
  for (int j = 0; j < 8; ++j)
#pragma unroll
    for (int m = 0; m < 4; ++m) acc2[j][m] = 0.f;

  const int ti = tq, di = sq;
  for (int h = 0; h < 2; ++h) {
    __syncthreads();  // h=0: P writes done; h=1: PV half0 sB reads done
#pragma unroll
    for (int it = 0; it < 4; ++it) {
      int r = it * 16 + rgrp;
      int srow = s_idx[h * 64 + r];
      float4 val = *reinterpret_cast<const float4*>(v + baseQ + (size_t)srow * D_N + c4);
      sB[r * 65 + c4 + 0] = val.x;
      sB[r * 65 + c4 + 1] = val.y;
      sB[r * 65 + c4 + 2] = val.z;
      sB[r * 65 + c4 + 3] = val.w;
    }
    __syncthreads();
    for (int s2 = 0; s2 < 64; ++s2) {
      int scol = h * 64 + s2;
      float pj[8], vm[4];
#pragma unroll
      for (int j = 0; j < 8; ++j) pj[j] = __half2float(sP[(8 * ti + j) * 132 + scol]);
#pragma unroll
      for (int m = 0; m < 4; ++m) vm[m] = sB[s2 * 65 + 4 * di + m];
#pragma unroll
      for (int j = 0; j < 8; ++j)
#pragma unroll
        for (int m = 0; m < 4; ++m) acc2[j][m] += pj[j] * vm[m];
    }
  }

  // ---- scatter to out (zeroed by kernel A)
#pragma unroll
  for (int j = 0; j < 8; ++j) {
    int row = 8 * ti + j;
    int srow = s_idx[row];
    float4 val;
    val.x = acc2[j][0]; val.y = acc2[j][1]; val.z = acc2[j][2]; val.w = acc2[j][3];
    *reinterpret_cast<float4*>(out + baseQ + (size_t)srow * D_N + 4 * di) = val;
  }
}

extern "C" void kernel_launch(void* const* d_in, const int* in_sizes, int n_in,
                              void* d_out, int out_size, void* d_ws, size_t ws_size,
                              hipStream_t stream) {
  const float* q = (const float*)d_in[0];
  const float* k = (const float*)d_in[1];
  const float* v = (const float*)d_in[2];
  float* out = (float*)d_out;
  double* imp = (double*)d_ws;  // 96*4096*8 = 3 MB scratch

  imp_zero_kernel<<<24576, 256, 0, stream>>>(q, out, imp);
  topk_attn_kernel<<<BH_N, 256, 0, stream>>>(q, k, v, imp, out);
}

// Round 2
// 307.806 us; speedup vs baseline: 1.0343x; 1.0343x over previous
//
#include <hip/hip_runtime.h>
#include <hip/hip_fp16.h>
#include <math.h>

#define BH_N 96
#define S_N 4096
#define D_N 64
#define TOPK 128

typedef unsigned long long ull;

__device__ __forceinline__ ull orderKey(double d) {
  ull u = (ull)__double_as_longlong(d);
  if (u & 0x8000000000000000ULL) u = ~u;
  else u |= 0x8000000000000000ULL;
  return u;  // monotone: a<b (double) <=> orderKey(a)<orderKey(b)
}

// ---------------------------------------------------------------------------
// Kernel A: importance (double mean + std ddof=1) -> u64 orderKey, + zero out.
// One block = 16 rows of 64 floats; 16 lanes per row; float4 per lane.
// HBM roofline carrier: 100 MB read + 100 MB write.
// ---------------------------------------------------------------------------
__global__ __launch_bounds__(256)
void imp_zero_kernel(const float* __restrict__ q, float* __restrict__ out,
                     ull* __restrict__ keys) {
  const int tid = threadIdx.x;
  const size_t off = (size_t)blockIdx.x * 1024 + (size_t)tid * 4;
  const float4 v = *reinterpret_cast<const float4*>(q + off);
  float4 z; z.x = z.y = z.z = z.w = 0.f;
  *reinterpret_cast<float4*>(out + off) = z;

  double s  = (double)v.x + (double)v.y + (double)v.z + (double)v.w;
  double ss = (double)v.x * v.x + (double)v.y * v.y +
              (double)v.z * v.z + (double)v.w * v.w;
#pragma unroll
  for (int m = 1; m < 16; m <<= 1) {
    s  += __shfl_xor(s, m, 64);
    ss += __shfl_xor(ss, m, 64);
  }
  if ((tid & 15) == 0) {
    double mean = s * (1.0 / 64.0);
    double var = (ss - s * s * (1.0 / 64.0)) * (1.0 / 63.0);
    if (var < 0.0) var = 0.0;
    keys[(size_t)blockIdx.x * 16 + (tid >> 4)] = orderKey(mean + sqrt(var));
  }
}

// ---------------------------------------------------------------------------
// Kernel B1: per-(b,h) exact top-128 via 64-bit threshold binary search.
// 1024 threads (16 waves), 4 keys/thread. Ballot counting (no shuffle tree),
// one barrier/iter via double-buffered partial-count slots.
// ---------------------------------------------------------------------------
__global__ __launch_bounds__(1024)
void sel_kernel(const ull* __restrict__ keys, int* __restrict__ idx_out) {
  __shared__ int red[2][16];
  __shared__ int s_idx[TOPK];
  __shared__ int s_tidx[1024];
  __shared__ int s_cnt, s_tcnt;

  const int tid = threadIdx.x;
  const int lane = tid & 63;
  const int wv = tid >> 6;
  const int bh = blockIdx.x;
  const ull* kb = keys + (size_t)bh * S_N;

  ull key[4];
#pragma unroll
  for (int i = 0; i < 4; ++i) key[i] = kb[i * 1024 + tid];

  if (tid == 0) { s_cnt = 0; s_tcnt = 0; }

  ull lo = 0ULL, hi = ~0ULL;
  int p = 0;
  while (lo < hi) {
    ull d = hi - lo;
    ull mid = lo + (d >> 1) + (d & 1ULL);  // ceil midpoint, overflow-safe
    int c = 0;
#pragma unroll
    for (int i = 0; i < 4; ++i) c += __popcll(__ballot(key[i] >= mid));
    if (lane == 0) red[p][wv] = c;
    __syncthreads();
    int total = 0;
#pragma unroll
    for (int w = 0; w < 16; ++w) total += red[p][w];
    if (total >= TOPK) lo = mid; else hi = mid - 1;
    p ^= 1;
  }
  const ull T = lo;

  // emit strictly-greater (order-free set), collect tie candidates
#pragma unroll
  for (int i = 0; i < 4; ++i) {
    if (key[i] > T) {
      int slot = atomicAdd(&s_cnt, 1);
      s_idx[slot] = i * 1024 + tid;
    } else if (key[i] == T) {
      int sl = atomicAdd(&s_tcnt, 1);
      if (sl < 1024) s_tidx[sl] = i * 1024 + tid;
    }
  }
  __syncthreads();
  const int nsel = s_cnt;
  const int need = TOPK - nsel;
  if (wv == 0 && need > 0) {
    int t = s_tcnt < 1024 ? s_tcnt : 1024;
    for (int sel = 0; sel < need; ++sel) {  // lowest indices first (top_k tie-break)
      int mymin = 0x7fffffff;
      for (int j = lane; j < t; j += 64) mymin = min(mymin, s_tidx[j]);
#pragma unroll
      for (int m = 1; m < 64; m <<= 1) mymin = min(mymin, __shfl_xor(mymin, m, 64));
      if (lane == 0) s_idx[nsel + sel] = mymin;
      for (int j = lane; j < t; j += 64)
        if (s_tidx[j] == mymin) s_tidx[j] = 0x7fffffff;
    }
  }
  __syncthreads();
  if (tid < TOPK) idx_out[bh * TOPK + tid] = s_idx[tid];
}

// ---------------------------------------------------------------------------
// Kernel B2: attention on selected rows. 4 blocks per (b,h), 32 q-rows each.
// 256 threads: rr=tid>>4 -> q-rows {2rr,2rr+1}; cc=tid&15 -> 4 cols per half.
// ---------------------------------------------------------------------------
__global__ __launch_bounds__(256)
void attn_kernel(const float* __restrict__ q, const float* __restrict__ k,
                 const float* __restrict__ v, const int* __restrict__ idx_all,
                 float* __restrict__ out) {
  __shared__ __align__(16) float sQ[32 * 65];
  __shared__ __align__(16) float sB[64 * 65];
  __shared__ __align__(16) __half sP[32 * 132];
  __shared__ int s_idx[TOPK];

  const int tid = threadIdx.x;
  const int bh = blockIdx.x >> 2;
  const int sub = blockIdx.x & 3;
  if (tid < TOPK) s_idx[tid] = idx_all[bh * TOPK + tid];

  const size_t base = (size_t)bh * S_N * D_N;
  const int rgrp = tid >> 4;        // 0..15
  const int c4 = (tid & 15) * 4;    // 0..60
  const int rr = tid >> 4;          // 0..15
  const int cc = tid & 15;          // 0..15

  __syncthreads();  // s_idx ready

  // gather 32 q rows -> sQ
#pragma unroll
  for (int it = 0; it < 2; ++it) {
    int r = it * 16 + rgrp;
    int srow = s_idx[sub * 32 + r];
    float4 val = *reinterpret_cast<const float4*>(q + base + (size_t)srow * D_N + c4);
    sQ[r * 65 + c4 + 0] = val.x; sQ[r * 65 + c4 + 1] = val.y;
    sQ[r * 65 + c4 + 2] = val.z; sQ[r * 65 + c4 + 3] = val.w;
  }

  // QK^T: acc[j][h*4+m] = row (2rr+j) x col (h*64 + cc*4 + m)
  float acc[2][8];
#pragma unroll
  for (int j = 0; j < 2; ++j)
#pragma unroll
    for (int m = 0; m < 8; ++m) acc[j][m] = 0.f;

  for (int h = 0; h < 2; ++h) {
    __syncthreads();
#pragma unroll
    for (int it = 0; it < 4; ++it) {
      int r = it * 16 + rgrp;
      int srow = s_idx[h * 64 + r];
      float4 val = *reinterpret_cast<const float4*>(k + base + (size_t)srow * D_N + c4);
      sB[r * 65 + c4 + 0] = val.x; sB[r * 65 + c4 + 1] = val.y;
      sB[r * 65 + c4 + 2] = val.z; sB[r * 65 + c4 + 3] = val.w;
    }
    __syncthreads();
    for (int kk = 0; kk < 64; kk += 2) {
#pragma unroll
      for (int u = 0; u < 2; ++u) {
        float qv0 = sQ[(2 * rr + 0) * 65 + kk + u];
        float qv1 = sQ[(2 * rr + 1) * 65 + kk + u];
        float kv[4];
#pragma unroll
        for (int m = 0; m < 4; ++m) kv[m] = sB[(cc * 4 + m) * 65 + kk + u];
#pragma unroll
        for (int m = 0; m < 4; ++m) {
          acc[0][h * 4 + m] += qv0 * kv[m];
          acc[1][h * 4 + m] += qv1 * kv[m];
        }
      }
    }
  }

  // softmax over rows 2rr, 2rr+1 (reduce across 16 consecutive lanes = cc)
  float rmax[2], rsum[2];
#pragma unroll
  for (int j = 0; j < 2; ++j) {
    float mx = acc[j][0];
#pragma unroll
    for (int m = 1; m < 8; ++m) mx = fmaxf(mx, acc[j][m]);
    rmax[j] = mx;
  }
#pragma unroll
  for (int mm = 1; mm < 16; mm <<= 1)
#pragma unroll
    for (int j = 0; j < 2; ++j) rmax[j] = fmaxf(rmax[j], __shfl_xor(rmax[j], mm, 64));
#pragma unroll
  for (int j = 0; j < 2; ++j) {
    float sum = 0.f;
#pragma unroll
    for (int m = 0; m < 8; ++m) {
      float pe = __expf(0.125f * (acc[j][m] - rmax[j]));
      acc[j][m] = pe;
      sum += pe;
    }
    rsum[j] = sum;
  }
#pragma unroll
  for (int mm = 1; mm < 16; mm <<= 1)
#pragma unroll
    for (int j = 0; j < 2; ++j) rsum[j] += __shfl_xor(rsum[j], mm, 64);
#pragma unroll
  for (int j = 0; j < 2; ++j) {
    float rinv = 1.f / rsum[j];
#pragma unroll
    for (int h2 = 0; h2 < 2; ++h2)
#pragma unroll
      for (int m = 0; m < 4; ++m) {
        int col = h2 * 64 + cc * 4 + m;
        sP[(2 * rr + j) * 132 + col] = __float2half_rn(acc[j][h2 * 4 + m] * rinv);
      }
  }

  // PV: acc2[j][m] = out row (2rr+j), d-col (cc*4+m)
  float acc2[2][4];
#pragma unroll
  for (int j = 0; j < 2; ++j)
#pragma unroll
    for (int m = 0; m < 4; ++m) acc2[j][m] = 0.f;

  for (int h = 0; h < 2; ++h) {
    __syncthreads();  // h=0: sP writes + last QK sB reads done; h=1: PV half0 sB reads done
#pragma unroll
    for (int it = 0; it < 4; ++it) {
      int r = it * 16 + rgrp;
      int srow = s_idx[h * 64 + r];
      float4 val = *reinterpret_cast<const float4*>(v + base + (size_t)srow * D_N + c4);
      sB[r * 65 + c4 + 0] = val.x; sB[r * 65 + c4 + 1] = val.y;
      sB[r * 65 + c4 + 2] = val.z; sB[r * 65 + c4 + 3] = val.w;
    }
    __syncthreads();
    for (int s2 = 0; s2 < 64; ++s2) {
      int scol = h * 64 + s2;
      float pj0 = __half2float(sP[(2 * rr + 0) * 132 + scol]);
      float pj1 = __half2float(sP[(2 * rr + 1) * 132 + scol]);
      float vm[4];
#pragma unroll
      for (int m = 0; m < 4; ++m) vm[m] = sB[s2 * 65 + cc * 4 + m];
#pragma unroll
      for (int m = 0; m < 4; ++m) {
        acc2[0][m] += pj0 * vm[m];
        acc2[1][m] += pj1 * vm[m];
      }
    }
  }

  // scatter
#pragma unroll
  for (int j = 0; j < 2; ++j) {
    int srow = s_idx[sub * 32 + 2 * rr + j];
    float4 val;
    val.x = acc2[j][0]; val.y = acc2[j][1]; val.z = acc2[j][2]; val.w = acc2[j][3];
    *reinterpret_cast<float4*>(out + base + (size_t)srow * D_N + cc * 4) = val;
  }
}

extern "C" void kernel_launch(void* const* d_in, const int* in_sizes, int n_in,
                              void* d_out, int out_size, void* d_ws, size_t ws_size,
                              hipStream_t stream) {
  const float* q = (const float*)d_in[0];
  const float* k = (const float*)d_in[1];
  const float* v = (const float*)d_in[2];
  float* out = (float*)d_out;
  ull* keys = (ull*)d_ws;                                   // 96*4096*8 = 3 MB
  int* idx = (int*)((char*)d_ws + (size_t)BH_N * S_N * 8);  // 96*128*4 = 48 KB

  imp_zero_kernel<<<24576, 256, 0, stream>>>(q, out, keys);
  sel_kernel<<<BH_N, 1024, 0, stream>>>(keys, idx);
  attn_kernel<<<BH_N * 4, 256, 0, stream>>>(q, k, v, idx, out);
}